// Round 4
// baseline (6157.521 us; speedup 1.0000x reference)
//
#include <hip/hip_runtime.h>
#include <math.h>
#include <stdint.h>

#define TT 64
#define OUTW 16896  // 512 + 4*4096

// ---------------- static device storage (re-filled every launch) ----------------
__device__ float WpreT[4098][512];   // W_pre^T  [k][j]
__device__ float WihT [512][1536];   // W_ih^T
__device__ float WhhT [512][1536];   // W_hh^T
__device__ float Wp1T [512][512];
__device__ float Wq1T [768][512];
__device__ float Wp2T [512][4096];
__device__ float Wq2T [512][4096];

// coherent-access-only arrays (only touched via cload/cstore in rssm_main)
__device__ float    g_h[2][32][512];   // deter state double buffer
__device__ float    g_xp[2][32][512];  // pre-GRU pre-activation partial sums (d-halves)
__device__ float    g_gx[32][1536];    // x @ W_ih^T (no bias)
__device__ float    g_gh[32][1536];    // h @ W_hh^T (no bias)
__device__ float    g_p1q1[32][1024];  // [0:512]=p1, [512:1024]=q1
__device__ unsigned g_qidx[32][64];    // posterior sample indices
__device__ unsigned g_flags[512 * 16]; // barrier arrival flags, 64B apart
__device__ unsigned g_go;              // barrier broadcast word

struct Params {
  const float *obs, *act, *b_pre, *b_ih, *b_hh, *b_p1, *b_p2, *b_q1, *b_q2;
  float* out;
};

// ---------------- coherent access helpers (relaxed, agent scope, no fences) ----------------
__device__ __forceinline__ float cload(const float* p) {
  return __hip_atomic_load((float*)p, __ATOMIC_RELAXED, __HIP_MEMORY_SCOPE_AGENT);
}
__device__ __forceinline__ void cstore(float* p, float v) {
  __hip_atomic_store(p, v, __ATOMIC_RELAXED, __HIP_MEMORY_SCOPE_AGENT);
}
__device__ __forceinline__ unsigned cuload(const unsigned* p) {
  return __hip_atomic_load((unsigned*)p, __ATOMIC_RELAXED, __HIP_MEMORY_SCOPE_AGENT);
}
__device__ __forceinline__ void custore(unsigned* p, unsigned v) {
  __hip_atomic_store(p, v, __ATOMIC_RELAXED, __HIP_MEMORY_SCOPE_AGENT);
}

// ---------------- misc helpers ----------------
__device__ __forceinline__ float rdlane(float v, int l) {
  return __int_as_float(__builtin_amdgcn_readlane(__float_as_int(v), l));
}
__device__ __forceinline__ float sigm(float x) { return 1.0f / (1.0f + expf(-x)); }
__device__ __forceinline__ float siluf(float x) { return x * sigm(x); }

// torch-GRUCell recompute from coherent gate buffers (bit-deterministic everywhere)
__device__ __forceinline__ float h2_of(const Params& P, const float* hprev, int b, int k) {
  float xr = cload(&g_gx[b][k]),        hr = cload(&g_gh[b][k]);
  float xu = cload(&g_gx[b][512 + k]),  hu = cload(&g_gh[b][512 + k]);
  float xn = cload(&g_gx[b][1024 + k]), hn = cload(&g_gh[b][1024 + k]);
  float r = sigm(xr + hr + P.b_ih[k] + P.b_hh[k]);
  float u = sigm(xu + hu + P.b_ih[512 + k] + P.b_hh[512 + k]);
  float n = tanhf(xn + P.b_ih[1024 + k] + r * (hn + P.b_hh[1024 + k]));
  return (1.0f - u) * n + u * cload(&hprev[b * 512 + k]);
}

// Threefry-2x32, 20 rounds, key = (0, 42)
__device__ __forceinline__ uint2 threefry_0_42(unsigned x0, unsigned x1) {
  const unsigned ks0 = 0u, ks1 = 42u, ks2 = 0x1BD11BDAu ^ 0u ^ 42u;
  x0 += ks0; x1 += ks1;
#define TFR(r) { x0 += x1; x1 = (x1 << r) | (x1 >> (32 - r)); x1 ^= x0; }
  TFR(13) TFR(15) TFR(26) TFR(6)   x0 += ks1; x1 += ks2 + 1u;
  TFR(17) TFR(29) TFR(16) TFR(24)  x0 += ks2; x1 += ks0 + 2u;
  TFR(13) TFR(15) TFR(26) TFR(6)   x0 += ks0; x1 += ks1 + 3u;
  TFR(17) TFR(29) TFR(16) TFR(24)  x0 += ks1; x1 += ks2 + 4u;
  TFR(13) TFR(15) TFR(26) TFR(6)   x0 += ks2; x1 += ks0 + 5u;
#undef TFR
  return make_uint2(x0, x1);
}
__device__ __forceinline__ unsigned jax_bits_partitionable(unsigned flat) {
  uint2 o = threefry_0_42(0u, flat);
  return o.x ^ o.y;
}

// ---------------- fence-free grid barrier (512 blocks) ----------------
__device__ __forceinline__ void gbar(int bid, int tid, unsigned p) {
  asm volatile("s_waitcnt vmcnt(0)" ::: "memory");
  __syncthreads();
  if (tid == 0) custore(&g_flags[bid * 16], p);
  if (bid == 0) {
    for (;;) {
      unsigned a = cuload(&g_flags[tid * 16]);
      unsigned b = cuload(&g_flags[(tid + 256) * 16]);
      if (a >= p && b >= p) break;
      __builtin_amdgcn_s_sleep(1);
    }
    __syncthreads();
    if (tid == 0) custore(&g_go, p);
  } else if (tid == 0) {
    while (cuload(&g_go) < p) __builtin_amdgcn_s_sleep(1);
  }
  __syncthreads();
  asm volatile("" ::: "memory");
}

// ---------------- setup kernels ----------------
__global__ void kzero() {
  unsigned i = blockIdx.x * 256 + threadIdx.x;  // 128 blocks -> i < 32768
  ((float*)g_h)[i] = 0.0f;
  if (i < 8192u) g_flags[i] = 0u;
  if (i == 0) g_go = 0u;
}

__device__ float* tr_dst(int sel) {
  switch (sel) {
    case 0: return &WpreT[0][0];
    case 1: return &WihT[0][0];
    case 2: return &WhhT[0][0];
    case 3: return &Wp1T[0][0];
    case 4: return &Wq1T[0][0];
    case 5: return &Wp2T[0][0];
    default: return &Wq2T[0][0];
  }
}

__global__ void ktranspose(const float* __restrict__ src, int sel, int R, int C) {
  __shared__ float tile[32][33];
  float* dst = tr_dst(sel);
  int c0 = blockIdx.x * 32, r0 = blockIdx.y * 32;
  int tx = threadIdx.x & 31, ty = threadIdx.x >> 5;
  for (int i = ty; i < 32; i += 8) {
    int r = r0 + i, c = c0 + tx;
    if (r < R && c < C) tile[i][tx] = src[(size_t)r * C + c];
  }
  __syncthreads();
  for (int i = ty; i < 32; i += 8) {
    int c = c0 + i, r = r0 + tx;
    if (c < C && r < R) dst[(size_t)c * R + r] = tile[tx][i];
  }
}

// ---------------- main persistent kernel: 512 blocks x 256 threads ----------------
__global__ void __launch_bounds__(256) rssm_main(Params P) {
  const int bid = blockIdx.x, tid = threadIdx.x;
  const int lane = tid & 63, kq = tid >> 6;
  const int x = bid & 7;              // XCD residue == weight-slice index
  __shared__ float lds[2560];
  unsigned ph = 0;

  // stage-D coordinates: 64 col-slices (128 cols) x 8 batch-quads
  const int dm = bid >> 3;            // 0..63
  const int dj = dm >> 3;             // 0..7
  const int dp = dm & 7;              // 0..7
  const int ds = x + 8 * dj;          // slice 0..63, ds%8 == x
  const int dn = ds >> 5;             // 0 prior / 1 posterior
  const int dcb = ds & 31;            // 128-col chunk
  const int dcolbase = dcb * 128;
  const int db0 = dp * 4;             // 4 batches per block
  const float* W2 = dn ? &Wq2T[0][0] : &Wp2T[0][0];

  for (int t = 0; t < TT; ++t) {
    const float* hprev = &g_h[t & 1][0][0];
    float* hnext = &g_h[(t + 1) & 1][0][0];

    // ===== STAGE A: gh (0..255) | prefetch D(j0..3)+Wq1 (256..383) | gather (384..511) =====
    if (bid < 256) {
      const int b = bid >> 3;
      const int c = x * 64 + lane;
      const int k0 = kq * 128;
      float a0 = 0, a1 = 0, a2 = 0;
      for (int kt = 0; kt < 128; kt += 64) {
        float v0 = cload(&hprev[b * 512 + k0 + kt + lane]);
#pragma unroll
        for (int kk = 0; kk < 64; ++kk) {
          const float* wr = &WhhT[k0 + kt + kk][c];
          float s0 = rdlane(v0, kk);
          a0 = fmaf(s0, wr[0], a0);
          a1 = fmaf(s0, wr[512], a1);
          a2 = fmaf(s0, wr[1024], a2);
        }
      }
      int base = (kq * 64 + lane) * 3;
      lds[base] = a0; lds[base + 1] = a1; lds[base + 2] = a2;
      __syncthreads();
      if (tid < 192) {
        int ln = tid & 63, g = tid >> 6;
        float s = lds[(0 * 64 + ln) * 3 + g] + lds[(1 * 64 + ln) * 3 + g] +
                  lds[(2 * 64 + ln) * 3 + g] + lds[(3 * 64 + ln) * 3 + g];
        cstore(&g_gh[b][g * 512 + x * 64 + ln], s);
      }
    } else if (bid >= 384) {
      // gather: rel 0..127: b = rel>>2, dh = (rel>>1)&1, chh = rel&1
      const int rel = bid - 384;
      const int b = rel >> 2, dh = (rel >> 1) & 1, chh = rel & 1;
      unsigned* qlds = (unsigned*)lds;
      if (t > 0 && tid < 64) qlds[tid] = cuload(&g_qidx[b][tid]);
      __syncthreads();
      const int jj = chh * 256 + tid;
      float acc = 0.0f;
      if (dh == 0) {
        float a0v = P.act[((size_t)b * TT + t) * 2 + 0];
        float a1v = P.act[((size_t)b * TT + t) * 2 + 1];
        acc = P.b_pre[jj] + a0v * WpreT[4096][jj] + a1v * WpreT[4097][jj];
      }
      if (t > 0) {
#pragma unroll 8
        for (int d2 = 0; d2 < 32; ++d2) {
          int d = dh * 32 + d2;
          acc += __builtin_nontemporal_load(&WpreT[(d << 6) + qlds[d]][jj]);
        }
      }
      cstore(&g_xp[dh][b][jj], acc);
    } else {
      // prefetch: D slices j'=0..3 (Wp2 fully) + Wq1 x-slice
      const int q = (bid >> 3) - 32;       // 0..15
      const int pj = q >> 2, sub = q & 3;
      const int ps = x + 8 * pj;           // 0..31 (n=0)
      const float* PW = (ps >= 32) ? &Wq2T[0][0] : &Wp2T[0][0];
      const int pcol = (ps & 31) * 128;
      float dummy = 0.f;
#pragma unroll
      for (int i = 0; i < 4; ++i) {
        int l = sub * 1024 + tid * 4 + i;  // line id 0..4095 within slice
        dummy += PW[(size_t)(l >> 3) * 4096 + pcol + (l & 7) * 16];
      }
      if (tid < 192) {
        int r = q * 48 + (tid >> 2);
        dummy += Wq1T[r][x * 64 + (tid & 3) * 16];
      }
      asm volatile("" :: "v"(dummy));
    }
    gbar(bid, tid, ++ph);

    // ===== STAGE B: gx (0..255) | prefetch all D slices (256..511) =====
    if (bid < 256) {
      const int b = bid >> 3;
      const int c = x * 64 + lane;
      const int k0 = kq * 128;
      float a0 = 0, a1 = 0, a2 = 0;
      for (int kt = 0; kt < 128; kt += 64) {
        int k = k0 + kt + lane;
        float v0 = siluf(cload(&g_xp[0][b][k]) + cload(&g_xp[1][b][k]));
#pragma unroll
        for (int kk = 0; kk < 64; ++kk) {
          const float* wr = &WihT[k0 + kt + kk][c];
          float s0 = rdlane(v0, kk);
          a0 = fmaf(s0, wr[0], a0);
          a1 = fmaf(s0, wr[512], a1);
          a2 = fmaf(s0, wr[1024], a2);
        }
      }
      int base = (kq * 64 + lane) * 3;
      lds[base] = a0; lds[base + 1] = a1; lds[base + 2] = a2;
      __syncthreads();
      if (tid < 192) {
        int ln = tid & 63, g = tid >> 6;
        float s = lds[(0 * 64 + ln) * 3 + g] + lds[(1 * 64 + ln) * 3 + g] +
                  lds[(2 * 64 + ln) * 3 + g] + lds[(3 * 64 + ln) * 3 + g];
        cstore(&g_gx[b][g * 512 + x * 64 + ln], s);
      }
    } else {
      const int q = (bid >> 3) - 32;       // 0..31
      const int pj = q >> 2, sub = q & 3;  // pj 0..7
      const int ps = x + 8 * pj;           // 0..63
      const float* PW = (ps >= 32) ? &Wq2T[0][0] : &Wp2T[0][0];
      const int pcol = (ps & 31) * 128;
      float dummy = 0.f;
#pragma unroll
      for (int i = 0; i < 4; ++i) {
        int l = sub * 1024 + tid * 4 + i;
        dummy += PW[(size_t)(l >> 3) * 4096 + pcol + (l & 7) * 16];
      }
      asm volatile("" :: "v"(dummy));
    }
    gbar(bid, tid, ++ph);

    // ===== STAGE C: p1 + h2 materialize (0..255) | q1 (256..511) =====
    if (bid < 256) {
      const int b = bid >> 3;
      const int c = x * 64 + lane;
      const int k0 = kq * 128;
      const bool mat = (x == (b & 7));
      float a0 = 0;
      for (int kt = 0; kt < 128; kt += 64) {
        int k = k0 + kt + lane;
        float v0 = h2_of(P, hprev, b, k);
        if (mat) {
          cstore(&hnext[b * 512 + k], v0);
          __builtin_nontemporal_store(v0, &P.out[((size_t)b * TT + t) * OUTW + k]);
        }
#pragma unroll
        for (int kk = 0; kk < 64; ++kk)
          a0 = fmaf(rdlane(v0, kk), Wp1T[k0 + kt + kk][c], a0);
      }
      lds[kq * 64 + lane] = a0;
      __syncthreads();
      if (tid < 64) {
        float s = lds[tid] + lds[64 + tid] + lds[128 + tid] + lds[192 + tid] +
                  P.b_p1[x * 64 + tid];
        cstore(&g_p1q1[b][x * 64 + tid], siluf(s));
      }
    } else {
      const int b = (bid >> 3) - 32;
      const int c = x * 64 + lane;
      const int k0 = kq * 192;
      float a0 = 0;
      for (int kt = 0; kt < 192; kt += 64) {
        int ks = k0 + kt;
        float v0 = (ks < 512)
            ? h2_of(P, hprev, b, ks + lane)
            : __builtin_nontemporal_load(&P.obs[((size_t)b * TT + t) * 256 + (ks - 512) + lane]);
#pragma unroll
        for (int kk = 0; kk < 64; ++kk)
          a0 = fmaf(rdlane(v0, kk), Wq1T[ks + kk][c], a0);
      }
      lds[kq * 64 + lane] = a0;
      __syncthreads();
      if (tid < 64) {
        float s = lds[tid] + lds[64 + tid] + lds[128 + tid] + lds[192 + tid] +
                  P.b_q1[x * 64 + tid];
        cstore(&g_p1q1[b][512 + x * 64 + tid], siluf(s));
      }
    }
    gbar(bid, tid, ++ph);

    // ===== STAGE D: logits + softmax + gumbel sample (all 512 blocks) =====
    {
      const float* bias2 = dn ? P.b_q2 : P.b_p2;
      const int k0 = kq * 128;
      float acc[4][2] = {{0}};
      for (int kt = 0; kt < 128; kt += 64) {
        float v[4];
#pragma unroll
        for (int i = 0; i < 4; ++i) v[i] = cload(&g_p1q1[db0 + i][dn * 512 + k0 + kt + lane]);
#pragma unroll
        for (int kk = 0; kk < 64; ++kk) {
          const float2 w = *(const float2*)&W2[(size_t)(k0 + kt + kk) * 4096 + dcolbase + lane * 2];
#pragma unroll
          for (int i = 0; i < 4; ++i) {
            float s = rdlane(v[i], kk);
            acc[i][0] = fmaf(s, w.x, acc[i][0]);
            acc[i][1] = fmaf(s, w.y, acc[i][1]);
          }
        }
      }
      float* red = lds;          // 2048 floats
      float* lg  = lds + 2048;   // 512 floats: logits [i][128]
      int rb = (kq * 64 + lane) * 8;
#pragma unroll
      for (int i = 0; i < 4; ++i) { red[rb + i * 2] = acc[i][0]; red[rb + i * 2 + 1] = acc[i][1]; }
      __syncthreads();
      for (int idx = tid; idx < 512; idx += 256) {
        int i = idx >> 7, cc = idx & 127;
        int ln = cc >> 1, j2 = cc & 1;
        float s = red[(0 * 64 + ln) * 8 + i * 2 + j2] + red[(1 * 64 + ln) * 8 + i * 2 + j2] +
                  red[(2 * 64 + ln) * 8 + i * 2 + j2] + red[(3 * 64 + ln) * 8 + i * 2 + j2];
        s += bias2[dcolbase + cc];
        lg[i * 128 + cc] = s;
        __builtin_nontemporal_store(
            s, &P.out[((size_t)(db0 + i) * TT + t) * OUTW + (dn ? 12800 : 8704) + dcolbase + cc]);
      }
      __syncthreads();
      const int b = db0 + kq;   // each wave samples its own batch row
      for (int r = 0; r < 2; ++r) {
        const int d = dcb * 2 + r;
        float L = lg[kq * 128 + r * 64 + lane];
        float m = L;
        for (int off = 1; off < 64; off <<= 1) m = fmaxf(m, __shfl_xor(m, off));
        float e = expf(L - m);
        float ssum = e;
        for (int off = 1; off < 64; off <<= 1) ssum += __shfl_xor(ssum, off);
        float p = 0.99f * (e / ssum) + (float)(0.01 / 64.0);
        unsigned flat = ((((unsigned)t * 32u + (unsigned)b) * 64u + (unsigned)d) * 64u +
                         (unsigned)lane) + ((unsigned)dn << 23);
        unsigned bits = jax_bits_partitionable(flat);
        float f = __uint_as_float((bits >> 9) | 0x3f800000u) - 1.0f;
        float u = fmaxf(1e-9f, f + 1e-9f);
        float g = -logf(-logf(u));
        float y = logf(p) + g;
        float vm = y; int idxm = lane;
        for (int off = 1; off < 64; off <<= 1) {
          float v2 = __shfl_xor(vm, off);
          int i2 = __shfl_xor(idxm, off);
          if (v2 > vm || (v2 == vm && i2 < idxm)) { vm = v2; idxm = i2; }
        }
        __builtin_nontemporal_store(
            (lane == idxm) ? 1.0f : 0.0f,
            &P.out[((size_t)b * TT + t) * OUTW + (dn ? 4608 : 512) + d * 64 + lane]);
        if (dn == 1 && lane == 0) custore(&g_qidx[b][d], (unsigned)idxm);
      }
    }
    gbar(bid, tid, ++ph);
  }
}

// ---------------- host ----------------
extern "C" void kernel_launch(void* const* d_in, const int* in_sizes, int n_in,
                              void* d_out, int out_size, void* d_ws, size_t ws_size,
                              hipStream_t stream) {
  const float* obs   = (const float*)d_in[0];
  const float* act   = (const float*)d_in[1];
  const float* W_pre = (const float*)d_in[2];
  const float* b_pre = (const float*)d_in[3];
  const float* W_ih  = (const float*)d_in[4];
  const float* b_ih  = (const float*)d_in[5];
  const float* W_hh  = (const float*)d_in[6];
  const float* b_hh  = (const float*)d_in[7];
  const float* W_p1  = (const float*)d_in[8];
  const float* b_p1  = (const float*)d_in[9];
  const float* W_p2  = (const float*)d_in[10];
  const float* b_p2  = (const float*)d_in[11];
  const float* W_q1  = (const float*)d_in[12];
  const float* b_q1  = (const float*)d_in[13];
  const float* W_q2  = (const float*)d_in[14];
  const float* b_q2  = (const float*)d_in[15];

  kzero<<<128, 256, 0, stream>>>();
  auto tg = [](int R, int C) { return dim3((unsigned)((C + 31) / 32), (unsigned)((R + 31) / 32)); };
  ktranspose<<<tg(512, 4098), 256, 0, stream>>>(W_pre, 0, 512, 4098);
  ktranspose<<<tg(1536, 512), 256, 0, stream>>>(W_ih, 1, 1536, 512);
  ktranspose<<<tg(1536, 512), 256, 0, stream>>>(W_hh, 2, 1536, 512);
  ktranspose<<<tg(512, 512), 256, 0, stream>>>(W_p1, 3, 512, 512);
  ktranspose<<<tg(512, 768), 256, 0, stream>>>(W_q1, 4, 512, 768);
  ktranspose<<<tg(4096, 512), 256, 0, stream>>>(W_p2, 5, 4096, 512);
  ktranspose<<<tg(4096, 512), 256, 0, stream>>>(W_q2, 6, 4096, 512);

  Params P{obs, act, b_pre, b_ih, b_hh, b_p1, b_p2, b_q1, b_q2, (float*)d_out};
  rssm_main<<<dim3(512), dim3(256), 0, stream>>>(P);
}

// Round 5
// 3984.960 us; speedup vs baseline: 1.5452x; 1.5452x over previous
//
#include <hip/hip_runtime.h>
#include <math.h>
#include <stdint.h>

#define TT 64
#define OUTW 16896  // 512 + 4*4096

// ---------------- static device storage (re-filled every launch) ----------------
__device__ float WpreT[4098][512];   // W_pre^T  [k][j]
__device__ float WihT [512][1536];   // W_ih^T
__device__ float WhhT [512][1536];   // W_hh^T
__device__ float Wp1T [512][512];
__device__ float Wq1T [768][512];
__device__ float Wp2T [512][4096];
__device__ float Wq2T [512][4096];

// coherent-access-only arrays (only touched via cload/cstore in rssm_main)
__device__ float    g_h[2][32][512];   // deter state double buffer
__device__ float    g_x[32][512];      // pre-GRU activation
__device__ float    g_gx[32][1536];    // x @ W_ih^T (no bias)
__device__ float    g_gh[32][1536];    // h @ W_hh^T (no bias)
__device__ float    g_p1q1[32][1024];  // [0:512]=p1, [512:1024]=q1
__device__ unsigned g_qidx[32][64];    // posterior sample indices
__device__ unsigned g_flags[256 * 16]; // barrier arrival flags, 64B apart
__device__ unsigned g_go;              // barrier broadcast word

struct Params {
  const float *obs, *act, *b_pre, *b_ih, *b_hh, *b_p1, *b_p2, *b_q1, *b_q2;
  float* out;
};

// ---------------- coherent access helpers (relaxed, agent scope, no fences) ----------------
__device__ __forceinline__ float cload(const float* p) {
  return __hip_atomic_load((float*)p, __ATOMIC_RELAXED, __HIP_MEMORY_SCOPE_AGENT);
}
__device__ __forceinline__ void cstore(float* p, float v) {
  __hip_atomic_store(p, v, __ATOMIC_RELAXED, __HIP_MEMORY_SCOPE_AGENT);
}
__device__ __forceinline__ unsigned cuload(const unsigned* p) {
  return __hip_atomic_load((unsigned*)p, __ATOMIC_RELAXED, __HIP_MEMORY_SCOPE_AGENT);
}
__device__ __forceinline__ void custore(unsigned* p, unsigned v) {
  __hip_atomic_store(p, v, __ATOMIC_RELAXED, __HIP_MEMORY_SCOPE_AGENT);
}

// ---------------- misc helpers ----------------
__device__ __forceinline__ float rdlane(float v, int l) {
  return __int_as_float(__builtin_amdgcn_readlane(__float_as_int(v), l));
}
__device__ __forceinline__ float sigm(float x) { return 1.0f / (1.0f + expf(-x)); }
__device__ __forceinline__ float siluf(float x) { return x * sigm(x); }

// torch-GRUCell recompute from coherent gate buffers
__device__ __forceinline__ float h2_of(const Params& P, const float* hprev, int b, int k) {
  float xr = cload(&g_gx[b][k]),        hr = cload(&g_gh[b][k]);
  float xu = cload(&g_gx[b][512 + k]),  hu = cload(&g_gh[b][512 + k]);
  float xn = cload(&g_gx[b][1024 + k]), hn = cload(&g_gh[b][1024 + k]);
  float r = sigm(xr + hr + P.b_ih[k] + P.b_hh[k]);
  float u = sigm(xu + hu + P.b_ih[512 + k] + P.b_hh[512 + k]);
  float n = tanhf(xn + P.b_ih[1024 + k] + r * (hn + P.b_hh[1024 + k]));
  return (1.0f - u) * n + u * cload(&hprev[b * 512 + k]);
}

// Threefry-2x32, 20 rounds, key = (0, 42)
__device__ __forceinline__ uint2 threefry_0_42(unsigned x0, unsigned x1) {
  const unsigned ks0 = 0u, ks1 = 42u, ks2 = 0x1BD11BDAu ^ 0u ^ 42u;
  x0 += ks0; x1 += ks1;
#define TFR(r) { x0 += x1; x1 = (x1 << r) | (x1 >> (32 - r)); x1 ^= x0; }
  TFR(13) TFR(15) TFR(26) TFR(6)   x0 += ks1; x1 += ks2 + 1u;
  TFR(17) TFR(29) TFR(16) TFR(24)  x0 += ks2; x1 += ks0 + 2u;
  TFR(13) TFR(15) TFR(26) TFR(6)   x0 += ks0; x1 += ks1 + 3u;
  TFR(17) TFR(29) TFR(16) TFR(24)  x0 += ks1; x1 += ks2 + 4u;
  TFR(13) TFR(15) TFR(26) TFR(6)   x0 += ks2; x1 += ks0 + 5u;
#undef TFR
  return make_uint2(x0, x1);
}
__device__ __forceinline__ unsigned jax_bits_partitionable(unsigned flat) {
  uint2 o = threefry_0_42(0u, flat);
  return o.x ^ o.y;
}

// ---------------- fence-free grid barrier (256 blocks) ----------------
__device__ __forceinline__ void gbar(int bid, int tid, unsigned p) {
  asm volatile("s_waitcnt vmcnt(0)" ::: "memory");
  __syncthreads();
  if (tid == 0) custore(&g_flags[bid * 16], p);
  if (bid == 0) {
    while (cuload(&g_flags[tid * 16]) < p) __builtin_amdgcn_s_sleep(1);
    __syncthreads();
    if (tid == 0) custore(&g_go, p);
  } else if (tid == 0) {
    while (cuload(&g_go) < p) __builtin_amdgcn_s_sleep(1);
  }
  __syncthreads();
  asm volatile("" ::: "memory");
}

// gate matmul: dst[b][g*512+c] = vec-row ⋅ W-col, 3 gates at once, 2 batch rows.
// rel = jb + ... with jb = rel&7 so XCD residue == weight-slice index.
__device__ __forceinline__ void gate_mm(const float (*W)[1536], const float* vec,
                                        float (*dst)[1536], int rel, int tid, float* lds) {
  const int lane = tid & 63, kq = tid >> 6;
  const int jb = rel & 7, bq = rel >> 3, b0 = bq * 2;
  const int c = jb * 64 + lane;
  const int k0 = kq * 128;
  float a00 = 0, a01 = 0, a10 = 0, a11 = 0, a20 = 0, a21 = 0;
  for (int kt = 0; kt < 128; kt += 64) {
    float v0 = cload(&vec[(b0 + 0) * 512 + k0 + kt + lane]);
    float v1 = cload(&vec[(b0 + 1) * 512 + k0 + kt + lane]);
#pragma unroll
    for (int kk = 0; kk < 64; ++kk) {
      const float* wr = &W[k0 + kt + kk][c];
      float w0 = wr[0], w1 = wr[512], w2 = wr[1024];
      float s0 = rdlane(v0, kk), s1 = rdlane(v1, kk);
      a00 = fmaf(s0, w0, a00); a01 = fmaf(s1, w0, a01);
      a10 = fmaf(s0, w1, a10); a11 = fmaf(s1, w1, a11);
      a20 = fmaf(s0, w2, a20); a21 = fmaf(s1, w2, a21);
    }
  }
  int base = (kq * 64 + lane) * 6;
  lds[base + 0] = a00; lds[base + 1] = a01; lds[base + 2] = a10;
  lds[base + 3] = a11; lds[base + 4] = a20; lds[base + 5] = a21;
  __syncthreads();
  for (int idx = tid; idx < 384; idx += 256) {
    int ln = idx % 64, w6 = idx / 64;
    float s = lds[(0 * 64 + ln) * 6 + w6] + lds[(1 * 64 + ln) * 6 + w6] +
              lds[(2 * 64 + ln) * 6 + w6] + lds[(3 * 64 + ln) * 6 + w6];
    int g = w6 >> 1, i = w6 & 1;
    cstore(&dst[b0 + i][g * 512 + jb * 64 + ln], s);
  }
}

// ---------------- setup kernels ----------------
__global__ void kzero() {
  unsigned i = blockIdx.x * 256 + threadIdx.x;  // 128 blocks -> i < 32768
  ((float*)g_h)[i] = 0.0f;
  if (i < 4096u) g_flags[i] = 0u;
  if (i == 0) g_go = 0u;
}

__device__ float* tr_dst(int sel) {
  switch (sel) {
    case 0: return &WpreT[0][0];
    case 1: return &WihT[0][0];
    case 2: return &WhhT[0][0];
    case 3: return &Wp1T[0][0];
    case 4: return &Wq1T[0][0];
    case 5: return &Wp2T[0][0];
    default: return &Wq2T[0][0];
  }
}

__global__ void ktranspose(const float* __restrict__ src, int sel, int R, int C) {
  __shared__ float tile[32][33];
  float* dst = tr_dst(sel);
  int c0 = blockIdx.x * 32, r0 = blockIdx.y * 32;
  int tx = threadIdx.x & 31, ty = threadIdx.x >> 5;
  for (int i = ty; i < 32; i += 8) {
    int r = r0 + i, c = c0 + tx;
    if (r < R && c < C) tile[i][tx] = src[(size_t)r * C + c];
  }
  __syncthreads();
  for (int i = ty; i < 32; i += 8) {
    int c = c0 + i, r = r0 + tx;
    if (c < C && r < R) dst[(size_t)c * R + r] = tile[tx][i];
  }
}

// ---------------- main persistent kernel: 256 blocks x 256 threads ----------------
__global__ void __launch_bounds__(256) rssm_main(Params P) {
  const int bid = blockIdx.x, tid = threadIdx.x;
  const int lane = tid & 63, kq = tid >> 6;
  __shared__ float ldsTile[16384];   // 64KB stage-D weight tile
  __shared__ float lds[2560];
  unsigned ph = 0;

  // stage-D coordinates: 32 slices (256 cols) x 8 batch-quads; slice%8 == bid%8 (XCD-stable)
  const int dbq = bid >> 5, dnc = bid & 31;
  const int dn = dnc >> 4, dcb = dnc & 15;
  const int db0 = dbq * 4;
  const int dcolbase = dcb * 256;
  const int myc = kq * 64 + lane;    // column within the 256-col chunk
  const float* W2 = dn ? &Wq2T[0][0] : &Wp2T[0][0];

  for (int t = 0; t < TT; ++t) {
    const float* hprev = &g_h[t & 1][0][0];
    float* hnext = &g_h[(t + 1) & 1][0][0];

    // ===== STAGE A: x (one-hot gather) on blocks 0..31 ; gh on 128..255 =====
    if (bid < 32) {
      const int b = bid;
      unsigned* qlds = (unsigned*)lds;
      if (t > 0 && tid < 64) qlds[tid] = cuload(&g_qidx[b][tid]);
      __syncthreads();
      float a0 = P.act[((size_t)b * TT + t) * 2 + 0];
      float a1 = P.act[((size_t)b * TT + t) * 2 + 1];
      for (int jj = tid; jj < 512; jj += 256) {
        float acc = P.b_pre[jj] + a0 * WpreT[4096][jj] + a1 * WpreT[4097][jj];
        if (t > 0) {
#pragma unroll 8
          for (int d = 0; d < 64; ++d)
            acc += __builtin_nontemporal_load(&WpreT[(d << 6) + qlds[d]][jj]);
        }
        cstore(&g_x[b][jj], siluf(acc));
      }
    } else if (bid >= 128) {
      gate_mm(WhhT, hprev, g_gh, bid - 128, tid, lds);
    }
    gbar(bid, tid, ++ph);

    // ===== STAGE B: gx on blocks 0..127 =====
    if (bid < 128) {
      gate_mm(WihT, &g_x[0][0], g_gx, bid, tid, lds);
    }
    gbar(bid, tid, ++ph);

    // ===== STAGE C: p1 (0..127), q1 (128..255); h2 materialized by jb==(bq&7) p1 blocks =====
    if (bid < 128) {
      const int jb = bid & 7, bq = bid >> 3, b0 = bq * 2;
      const int c = jb * 64 + lane;
      const int k0 = kq * 128;
      const bool mat = (jb == (bq & 7));
      float a0 = 0, a1 = 0;
      for (int kt = 0; kt < 128; kt += 64) {
        int k = k0 + kt + lane;
        float v0 = h2_of(P, hprev, b0 + 0, k);
        float v1 = h2_of(P, hprev, b0 + 1, k);
        if (mat) {
          cstore(&hnext[(b0 + 0) * 512 + k], v0);
          cstore(&hnext[(b0 + 1) * 512 + k], v1);
          __builtin_nontemporal_store(v0, &P.out[((size_t)(b0 + 0) * TT + t) * OUTW + k]);
          __builtin_nontemporal_store(v1, &P.out[((size_t)(b0 + 1) * TT + t) * OUTW + k]);
        }
#pragma unroll
        for (int kk = 0; kk < 64; ++kk) {
          float w = Wp1T[k0 + kt + kk][c];
          a0 = fmaf(rdlane(v0, kk), w, a0);
          a1 = fmaf(rdlane(v1, kk), w, a1);
        }
      }
      int base = (kq * 64 + lane) * 2;
      lds[base] = a0; lds[base + 1] = a1;
      __syncthreads();
      for (int idx = tid; idx < 128; idx += 256) {
        int ln = idx & 63, i = idx >> 6;
        float s = lds[(0 * 64 + ln) * 2 + i] + lds[(1 * 64 + ln) * 2 + i] +
                  lds[(2 * 64 + ln) * 2 + i] + lds[(3 * 64 + ln) * 2 + i];
        s += P.b_p1[jb * 64 + ln];
        cstore(&g_p1q1[b0 + i][jb * 64 + ln], siluf(s));
      }
    } else {
      const int rel = bid - 128;
      const int jb = rel & 7, bq = rel >> 3, b0 = bq * 2;
      const int c = jb * 64 + lane;
      const int k0 = kq * 192;
      float a0 = 0, a1 = 0;
      for (int kt = 0; kt < 192; kt += 64) {
        int ks = k0 + kt;
        float v0, v1;
        if (ks < 512) {
          v0 = h2_of(P, hprev, b0 + 0, ks + lane);
          v1 = h2_of(P, hprev, b0 + 1, ks + lane);
        } else {
          v0 = __builtin_nontemporal_load(&P.obs[((size_t)(b0 + 0) * TT + t) * 256 + (ks - 512) + lane]);
          v1 = __builtin_nontemporal_load(&P.obs[((size_t)(b0 + 1) * TT + t) * 256 + (ks - 512) + lane]);
        }
#pragma unroll
        for (int kk = 0; kk < 64; ++kk) {
          float w = Wq1T[ks + kk][c];
          a0 = fmaf(rdlane(v0, kk), w, a0);
          a1 = fmaf(rdlane(v1, kk), w, a1);
        }
      }
      int base = (kq * 64 + lane) * 2;
      lds[base] = a0; lds[base + 1] = a1;
      __syncthreads();
      for (int idx = tid; idx < 128; idx += 256) {
        int ln = idx & 63, i = idx >> 6;
        float s = lds[(0 * 64 + ln) * 2 + i] + lds[(1 * 64 + ln) * 2 + i] +
                  lds[(2 * 64 + ln) * 2 + i] + lds[(3 * 64 + ln) * 2 + i];
        s += P.b_q1[jb * 64 + ln];
        cstore(&g_p1q1[b0 + i][512 + jb * 64 + ln], siluf(s));
      }
    }
    gbar(bid, tid, ++ph);

    // ===== STAGE D: LDS-staged logits + softmax + gumbel sample (all 256 blocks) =====
    {
      const float* bias2 = dn ? P.b_q2 : P.b_p2;
      float acc0 = 0, acc1 = 0, acc2 = 0, acc3 = 0;
      for (int tk = 0; tk < 8; ++tk) {
        const int kb = tk * 64;
        // bulk-stage 64x256 weight tile (64KB) with 16 independent float4 loads/thread
        const float* src = &W2[(size_t)kb * 4096 + dcolbase];
#pragma unroll
        for (int i = 0; i < 16; ++i) {
          int f = tid + i * 256;          // float4 index: row = f>>6, col4 = f&63
          int r = f >> 6, c4 = f & 63;
          *(float4*)&ldsTile[r * 256 + c4 * 4] =
              *(const float4*)&src[(size_t)r * 4096 + c4 * 4];
        }
        // activation slice for k = kb + lane (coherent; independent of ldsTile)
        float v0 = cload(&g_p1q1[db0 + 0][dn * 512 + kb + lane]);
        float v1 = cload(&g_p1q1[db0 + 1][dn * 512 + kb + lane]);
        float v2 = cload(&g_p1q1[db0 + 2][dn * 512 + kb + lane]);
        float v3 = cload(&g_p1q1[db0 + 3][dn * 512 + kb + lane]);
        __syncthreads();
#pragma unroll
        for (int kk = 0; kk < 64; ++kk) {
          float w = ldsTile[kk * 256 + myc];
          acc0 = fmaf(rdlane(v0, kk), w, acc0);
          acc1 = fmaf(rdlane(v1, kk), w, acc1);
          acc2 = fmaf(rdlane(v2, kk), w, acc2);
          acc3 = fmaf(rdlane(v3, kk), w, acc3);
        }
        __syncthreads();
      }
      float* lg = lds;   // 1024 floats: logits [i][256]
      float bb = bias2[dcolbase + myc];
      float s0 = acc0 + bb, s1 = acc1 + bb, s2 = acc2 + bb, s3 = acc3 + bb;
      lg[0 * 256 + myc] = s0;
      lg[1 * 256 + myc] = s1;
      lg[2 * 256 + myc] = s2;
      lg[3 * 256 + myc] = s3;
      const size_t obase = (dn ? 12800 : 8704) + dcolbase + myc;
      __builtin_nontemporal_store(s0, &P.out[((size_t)(db0 + 0) * TT + t) * OUTW + obase]);
      __builtin_nontemporal_store(s1, &P.out[((size_t)(db0 + 1) * TT + t) * OUTW + obase]);
      __builtin_nontemporal_store(s2, &P.out[((size_t)(db0 + 2) * TT + t) * OUTW + obase]);
      __builtin_nontemporal_store(s3, &P.out[((size_t)(db0 + 3) * TT + t) * OUTW + obase]);
      __syncthreads();
      const int b = db0 + kq;   // each wave samples its own batch row
      for (int r = 0; r < 4; ++r) {
        const int d = dcb * 4 + r;
        float L = lg[kq * 256 + r * 64 + lane];
        float m = L;
        for (int off = 1; off < 64; off <<= 1) m = fmaxf(m, __shfl_xor(m, off));
        float e = expf(L - m);
        float ssum = e;
        for (int off = 1; off < 64; off <<= 1) ssum += __shfl_xor(ssum, off);
        float p = 0.99f * (e / ssum) + (float)(0.01 / 64.0);
        unsigned flat = ((((unsigned)t * 32u + (unsigned)b) * 64u + (unsigned)d) * 64u +
                         (unsigned)lane) + ((unsigned)dn << 23);
        unsigned bits = jax_bits_partitionable(flat);
        float f = __uint_as_float((bits >> 9) | 0x3f800000u) - 1.0f;
        float u = fmaxf(1e-9f, f + 1e-9f);
        float g = -logf(-logf(u));
        float y = logf(p) + g;
        float vm = y; int idxm = lane;
        for (int off = 1; off < 64; off <<= 1) {
          float v2s = __shfl_xor(vm, off);
          int i2 = __shfl_xor(idxm, off);
          if (v2s > vm || (v2s == vm && i2 < idxm)) { vm = v2s; idxm = i2; }
        }
        __builtin_nontemporal_store(
            (lane == idxm) ? 1.0f : 0.0f,
            &P.out[((size_t)b * TT + t) * OUTW + (dn ? 4608 : 512) + d * 64 + lane]);
        if (dn == 1 && lane == 0) custore(&g_qidx[b][d], (unsigned)idxm);
      }
    }
    gbar(bid, tid, ++ph);
  }
}

// ---------------- host ----------------
extern "C" void kernel_launch(void* const* d_in, const int* in_sizes, int n_in,
                              void* d_out, int out_size, void* d_ws, size_t ws_size,
                              hipStream_t stream) {
  const float* obs   = (const float*)d_in[0];
  const float* act   = (const float*)d_in[1];
  const float* W_pre = (const float*)d_in[2];
  const float* b_pre = (const float*)d_in[3];
  const float* W_ih  = (const float*)d_in[4];
  const float* b_ih  = (const float*)d_in[5];
  const float* W_hh  = (const float*)d_in[6];
  const float* b_hh  = (const float*)d_in[7];
  const float* W_p1  = (const float*)d_in[8];
  const float* b_p1  = (const float*)d_in[9];
  const float* W_p2  = (const float*)d_in[10];
  const float* b_p2  = (const float*)d_in[11];
  const float* W_q1  = (const float*)d_in[12];
  const float* b_q1  = (const float*)d_in[13];
  const float* W_q2  = (const float*)d_in[14];
  const float* b_q2  = (const float*)d_in[15];

  kzero<<<128, 256, 0, stream>>>();
  auto tg = [](int R, int C) { return dim3((unsigned)((C + 31) / 32), (unsigned)((R + 31) / 32)); };
  ktranspose<<<tg(512, 4098), 256, 0, stream>>>(W_pre, 0, 512, 4098);
  ktranspose<<<tg(1536, 512), 256, 0, stream>>>(W_ih, 1, 1536, 512);
  ktranspose<<<tg(1536, 512), 256, 0, stream>>>(W_hh, 2, 1536, 512);
  ktranspose<<<tg(512, 512), 256, 0, stream>>>(W_p1, 3, 512, 512);
  ktranspose<<<tg(512, 768), 256, 0, stream>>>(W_q1, 4, 512, 768);
  ktranspose<<<tg(4096, 512), 256, 0, stream>>>(W_p2, 5, 4096, 512);
  ktranspose<<<tg(4096, 512), 256, 0, stream>>>(W_q2, 6, 4096, 512);

  Params P{obs, act, b_pre, b_ih, b_hh, b_p1, b_p2, b_q1, b_q2, (float*)d_out};
  rssm_main<<<dim3(256), dim3(256), 0, stream>>>(P);
}

// Round 6
// 3554.230 us; speedup vs baseline: 1.7324x; 1.1212x over previous
//
#include <hip/hip_runtime.h>
#include <math.h>
#include <stdint.h>

#define TT 64
#define OUTW 16896  // 512 + 4*4096

// ---------------- static device storage (re-filled every launch) ----------------
// Weights repacked into per-consumer-block CONTIGUOUS slices (L2 set-friendly).
__device__ float WpreT[4098][512];     // W_pre^T [k][j] (gather rows contiguous 2KB)
__device__ float WihR [8][512][192];   // slice x: [k][g*64+cc], col = g*512+x*64+cc
__device__ float WhhR [8][512][192];
__device__ float Wp1R [8][512][64];    // slice x: [k][cc], col = x*64+cc
__device__ float Wq1R [8][768][64];
__device__ float Wp2R [16][512][256];  // slice s: [k][cc], col = s*256+cc
__device__ float Wq2R [16][512][256];

// coherent-access-only arrays (only touched via cload/cstore in rssm_main)
__device__ float    g_h[2][32][512];   // deter state double buffer
__device__ float    g_x[32][512];      // pre-GRU activation
__device__ float    g_gx[32][1536];    // x @ W_ih^T (no bias)
__device__ float    g_gh[32][1536];    // h @ W_hh^T (no bias)
__device__ float    g_p1q1[32][1024];  // [0:512]=p1, [512:1024]=q1
__device__ unsigned g_qidx[32][64];    // posterior sample indices
__device__ unsigned g_flags[256 * 16]; // barrier arrival flags, 64B apart
__device__ unsigned g_go;              // barrier broadcast word

struct Params {
  const float *obs, *act, *b_pre, *b_ih, *b_hh, *b_p1, *b_p2, *b_q1, *b_q2;
  float* out;
};

// ---------------- coherent access helpers (relaxed, agent scope, no fences) ----------------
__device__ __forceinline__ float cload(const float* p) {
  return __hip_atomic_load((float*)p, __ATOMIC_RELAXED, __HIP_MEMORY_SCOPE_AGENT);
}
__device__ __forceinline__ void cstore(float* p, float v) {
  __hip_atomic_store(p, v, __ATOMIC_RELAXED, __HIP_MEMORY_SCOPE_AGENT);
}
__device__ __forceinline__ unsigned cuload(const unsigned* p) {
  return __hip_atomic_load((unsigned*)p, __ATOMIC_RELAXED, __HIP_MEMORY_SCOPE_AGENT);
}
__device__ __forceinline__ void custore(unsigned* p, unsigned v) {
  __hip_atomic_store(p, v, __ATOMIC_RELAXED, __HIP_MEMORY_SCOPE_AGENT);
}

// ---------------- misc helpers ----------------
__device__ __forceinline__ float rdlane(float v, int l) {
  return __int_as_float(__builtin_amdgcn_readlane(__float_as_int(v), l));
}
__device__ __forceinline__ float sigm(float x) { return 1.0f / (1.0f + expf(-x)); }
__device__ __forceinline__ float siluf(float x) { return x * sigm(x); }

// torch-GRUCell recompute from coherent gate buffers
__device__ __forceinline__ float h2_of(const Params& P, const float* hprev, int b, int k) {
  float xr = cload(&g_gx[b][k]),        hr = cload(&g_gh[b][k]);
  float xu = cload(&g_gx[b][512 + k]),  hu = cload(&g_gh[b][512 + k]);
  float xn = cload(&g_gx[b][1024 + k]), hn = cload(&g_gh[b][1024 + k]);
  float r = sigm(xr + hr + P.b_ih[k] + P.b_hh[k]);
  float u = sigm(xu + hu + P.b_ih[512 + k] + P.b_hh[512 + k]);
  float n = tanhf(xn + P.b_ih[1024 + k] + r * (hn + P.b_hh[1024 + k]));
  return (1.0f - u) * n + u * cload(&hprev[b * 512 + k]);
}

// Threefry-2x32, 20 rounds, key = (0, 42)
__device__ __forceinline__ uint2 threefry_0_42(unsigned x0, unsigned x1) {
  const unsigned ks0 = 0u, ks1 = 42u, ks2 = 0x1BD11BDAu ^ 0u ^ 42u;
  x0 += ks0; x1 += ks1;
#define TFR(r) { x0 += x1; x1 = (x1 << r) | (x1 >> (32 - r)); x1 ^= x0; }
  TFR(13) TFR(15) TFR(26) TFR(6)   x0 += ks1; x1 += ks2 + 1u;
  TFR(17) TFR(29) TFR(16) TFR(24)  x0 += ks2; x1 += ks0 + 2u;
  TFR(13) TFR(15) TFR(26) TFR(6)   x0 += ks0; x1 += ks1 + 3u;
  TFR(17) TFR(29) TFR(16) TFR(24)  x0 += ks1; x1 += ks2 + 4u;
  TFR(13) TFR(15) TFR(26) TFR(6)   x0 += ks2; x1 += ks0 + 5u;
#undef TFR
  return make_uint2(x0, x1);
}
__device__ __forceinline__ unsigned jax_bits_partitionable(unsigned flat) {
  uint2 o = threefry_0_42(0u, flat);
  return o.x ^ o.y;
}

// ---------------- fence-free grid barrier (256 blocks) ----------------
__device__ __forceinline__ void gbar(int bid, int tid, unsigned p) {
  asm volatile("s_waitcnt vmcnt(0)" ::: "memory");
  __syncthreads();
  if (tid == 0) custore(&g_flags[bid * 16], p);
  if (bid == 0) {
    while (cuload(&g_flags[tid * 16]) < p) __builtin_amdgcn_s_sleep(1);
    __syncthreads();
    if (tid == 0) custore(&g_go, p);
  } else if (tid == 0) {
    while (cuload(&g_go) < p) __builtin_amdgcn_s_sleep(1);
  }
  __syncthreads();
  asm volatile("" ::: "memory");
}

// gate matmul on repacked slice Wsl = [512][192] (contiguous 384KB):
// dst[b][g*512 + x*64 + ln] = sum_k vec[b][k] * Wsl[k][g*64+ln], 3 gates, 2 batch rows.
__device__ __forceinline__ void gate_mm(const float* Wsl, const float* vec,
                                        float (*dst)[1536], int rel, int tid, float* lds) {
  const int lane = tid & 63, kq = tid >> 6;
  const int jb = rel & 7, bq = rel >> 3, b0 = bq * 2;
  const int k0 = kq * 128;
  float a00 = 0, a01 = 0, a10 = 0, a11 = 0, a20 = 0, a21 = 0;
  for (int kt = 0; kt < 128; kt += 64) {
    float v0 = cload(&vec[(b0 + 0) * 512 + k0 + kt + lane]);
    float v1 = cload(&vec[(b0 + 1) * 512 + k0 + kt + lane]);
#pragma unroll
    for (int kk = 0; kk < 64; ++kk) {
      const float* wr = &Wsl[(size_t)(k0 + kt + kk) * 192 + lane];
      float w0 = wr[0], w1 = wr[64], w2 = wr[128];
      float s0 = rdlane(v0, kk), s1 = rdlane(v1, kk);
      a00 = fmaf(s0, w0, a00); a01 = fmaf(s1, w0, a01);
      a10 = fmaf(s0, w1, a10); a11 = fmaf(s1, w1, a11);
      a20 = fmaf(s0, w2, a20); a21 = fmaf(s1, w2, a21);
    }
  }
  int base = (kq * 64 + lane) * 6;
  lds[base + 0] = a00; lds[base + 1] = a01; lds[base + 2] = a10;
  lds[base + 3] = a11; lds[base + 4] = a20; lds[base + 5] = a21;
  __syncthreads();
  for (int idx = tid; idx < 384; idx += 256) {
    int ln = idx % 64, w6 = idx / 64;
    float s = lds[(0 * 64 + ln) * 6 + w6] + lds[(1 * 64 + ln) * 6 + w6] +
              lds[(2 * 64 + ln) * 6 + w6] + lds[(3 * 64 + ln) * 6 + w6];
    int g = w6 >> 1, i = w6 & 1;
    cstore(&dst[b0 + i][g * 512 + jb * 64 + ln], s);
  }
}

// ---------------- setup kernels ----------------
__global__ void kzero() {
  unsigned i = blockIdx.x * 256 + threadIdx.x;  // 128 blocks -> i < 32768
  ((float*)g_h)[i] = 0.0f;
  if (i < 4096u) g_flags[i] = 0u;
  if (i == 0) g_go = 0u;
}

__device__ float* tr_dst(int sel) {
  switch (sel) {
    case 0: return &WpreT[0][0];
    case 1: return &WihR[0][0][0];
    case 2: return &WhhR[0][0][0];
    case 3: return &Wp1R[0][0][0];
    case 4: return &Wq1R[0][0][0];
    case 5: return &Wp2R[0][0][0];
    default: return &Wq2R[0][0][0];
  }
}

// dst flat index for src element (r = output-column, c = k)
__device__ __forceinline__ size_t repack_index(int sel, int r, int c) {
  switch (sel) {
    case 0: return (size_t)c * 512 + r;                       // WpreT[4098][512]
    case 1: case 2: {                                         // [8][512][192]
      int g = r >> 9, x = (r >> 6) & 7, cc = r & 63;
      return ((size_t)x * 512 + c) * 192 + g * 64 + cc;
    }
    case 3: { int x = r >> 6, cc = r & 63; return ((size_t)x * 512 + c) * 64 + cc; }
    case 4: { int x = r >> 6, cc = r & 63; return ((size_t)x * 768 + c) * 64 + cc; }
    default: { int s = r >> 8, cc = r & 255; return ((size_t)s * 512 + c) * 256 + cc; }
  }
}

__global__ void ktranspose(const float* __restrict__ src, int sel, int R, int C) {
  __shared__ float tile[32][33];
  float* dst = tr_dst(sel);
  int c0 = blockIdx.x * 32, r0 = blockIdx.y * 32;
  int tx = threadIdx.x & 31, ty = threadIdx.x >> 5;
  for (int i = ty; i < 32; i += 8) {
    int r = r0 + i, c = c0 + tx;
    if (r < R && c < C) tile[i][tx] = src[(size_t)r * C + c];
  }
  __syncthreads();
  for (int i = ty; i < 32; i += 8) {
    int c = c0 + i, r = r0 + tx;
    if (c < C && r < R) dst[repack_index(sel, r, c)] = tile[tx][i];
  }
}

// ---------------- main persistent kernel: 256 blocks x 256 threads ----------------
__global__ void __launch_bounds__(256) rssm_main(Params P) {
  const int bid = blockIdx.x, tid = threadIdx.x;
  const int lane = tid & 63, kq = tid >> 6;
  __shared__ float ldsTile[16384];   // 64KB stage-D weight tile
  __shared__ float lds[2560];
  unsigned ph = 0;

  // stage-D coordinates: 32 slices (256 cols) x 8 batch-quads; slice%8 == bid%8 (XCD-stable)
  const int dbq = bid >> 5, dnc = bid & 31;
  const int dn = dnc >> 4, dcb = dnc & 15;
  const int db0 = dbq * 4;
  const int dcolbase = dcb * 256;
  const int myc = kq * 64 + lane;    // column within the 256-col chunk
  const float* W2sl = dn ? &Wq2R[dcb][0][0] : &Wp2R[dcb][0][0];  // contiguous 512KB slice

  for (int t = 0; t < TT; ++t) {
    const float* hprev = &g_h[t & 1][0][0];
    float* hnext = &g_h[(t + 1) & 1][0][0];

    // ===== STAGE A: x (one-hot gather) on blocks 0..31 ; gh on 128..255 =====
    if (bid < 32) {
      const int b = bid;
      unsigned* qlds = (unsigned*)lds;
      if (t > 0 && tid < 64) qlds[tid] = cuload(&g_qidx[b][tid]);
      __syncthreads();
      float a0 = P.act[((size_t)b * TT + t) * 2 + 0];
      float a1 = P.act[((size_t)b * TT + t) * 2 + 1];
      for (int jj = tid; jj < 512; jj += 256) {
        float acc = P.b_pre[jj] + a0 * WpreT[4096][jj] + a1 * WpreT[4097][jj];
        if (t > 0) {
#pragma unroll 8
          for (int d = 0; d < 64; ++d)
            acc += __builtin_nontemporal_load(&WpreT[(d << 6) + qlds[d]][jj]);
        }
        cstore(&g_x[b][jj], siluf(acc));
      }
    } else if (bid >= 128) {
      const int rel = bid - 128;
      gate_mm(&WhhR[rel & 7][0][0], hprev, g_gh, rel, tid, lds);
    }
    gbar(bid, tid, ++ph);

    // ===== STAGE B: gx on blocks 0..127 =====
    if (bid < 128) {
      gate_mm(&WihR[bid & 7][0][0], &g_x[0][0], g_gx, bid, tid, lds);
    }
    gbar(bid, tid, ++ph);

    // ===== STAGE C: p1 (0..127), q1 (128..255); h2 materialized by jb==(bq&7) p1 blocks =====
    if (bid < 128) {
      const int jb = bid & 7, bq = bid >> 3, b0 = bq * 2;
      const float* W1sl = &Wp1R[jb][0][0];   // [512][64]
      const int k0 = kq * 128;
      const bool mat = (jb == (bq & 7));
      float a0 = 0, a1 = 0;
      for (int kt = 0; kt < 128; kt += 64) {
        int k = k0 + kt + lane;
        float v0 = h2_of(P, hprev, b0 + 0, k);
        float v1 = h2_of(P, hprev, b0 + 1, k);
        if (mat) {
          cstore(&hnext[(b0 + 0) * 512 + k], v0);
          cstore(&hnext[(b0 + 1) * 512 + k], v1);
          __builtin_nontemporal_store(v0, &P.out[((size_t)(b0 + 0) * TT + t) * OUTW + k]);
          __builtin_nontemporal_store(v1, &P.out[((size_t)(b0 + 1) * TT + t) * OUTW + k]);
        }
#pragma unroll
        for (int kk = 0; kk < 64; ++kk) {
          float w = W1sl[(size_t)(k0 + kt + kk) * 64 + lane];
          a0 = fmaf(rdlane(v0, kk), w, a0);
          a1 = fmaf(rdlane(v1, kk), w, a1);
        }
      }
      int base = (kq * 64 + lane) * 2;
      lds[base] = a0; lds[base + 1] = a1;
      __syncthreads();
      for (int idx = tid; idx < 128; idx += 256) {
        int ln = idx & 63, i = idx >> 6;
        float s = lds[(0 * 64 + ln) * 2 + i] + lds[(1 * 64 + ln) * 2 + i] +
                  lds[(2 * 64 + ln) * 2 + i] + lds[(3 * 64 + ln) * 2 + i];
        s += P.b_p1[jb * 64 + ln];
        cstore(&g_p1q1[b0 + i][jb * 64 + ln], siluf(s));
      }
    } else {
      const int rel = bid - 128;
      const int jb = rel & 7, bq = rel >> 3, b0 = bq * 2;
      const float* Wq1sl = &Wq1R[jb][0][0];  // [768][64]
      const int k0 = kq * 192;
      float a0 = 0, a1 = 0;
      for (int kt = 0; kt < 192; kt += 64) {
        int ks = k0 + kt;
        float v0, v1;
        if (ks < 512) {
          v0 = h2_of(P, hprev, b0 + 0, ks + lane);
          v1 = h2_of(P, hprev, b0 + 1, ks + lane);
        } else {
          v0 = __builtin_nontemporal_load(&P.obs[((size_t)(b0 + 0) * TT + t) * 256 + (ks - 512) + lane]);
          v1 = __builtin_nontemporal_load(&P.obs[((size_t)(b0 + 1) * TT + t) * 256 + (ks - 512) + lane]);
        }
#pragma unroll
        for (int kk = 0; kk < 64; ++kk) {
          float w = Wq1sl[(size_t)(ks + kk) * 64 + lane];
          a0 = fmaf(rdlane(v0, kk), w, a0);
          a1 = fmaf(rdlane(v1, kk), w, a1);
        }
      }
      int base = (kq * 64 + lane) * 2;
      lds[base] = a0; lds[base + 1] = a1;
      __syncthreads();
      for (int idx = tid; idx < 128; idx += 256) {
        int ln = idx & 63, i = idx >> 6;
        float s = lds[(0 * 64 + ln) * 2 + i] + lds[(1 * 64 + ln) * 2 + i] +
                  lds[(2 * 64 + ln) * 2 + i] + lds[(3 * 64 + ln) * 2 + i];
        s += P.b_q1[jb * 64 + ln];
        cstore(&g_p1q1[b0 + i][512 + jb * 64 + ln], siluf(s));
      }
    }
    gbar(bid, tid, ++ph);

    // ===== STAGE D: LDS-staged logits + softmax + gumbel sample (all 256 blocks) =====
    {
      const float* bias2 = dn ? P.b_q2 : P.b_p2;
      float acc0 = 0, acc1 = 0, acc2 = 0, acc3 = 0;
      for (int tk = 0; tk < 8; ++tk) {
        const int kb = tk * 64;
        // bulk-stage contiguous 64KB tile: [64 rows][256 cols]
        const float4* src4 = (const float4*)(W2sl + (size_t)kb * 256);
        float4* dst4 = (float4*)ldsTile;
#pragma unroll
        for (int i = 0; i < 16; ++i) dst4[tid + i * 256] = src4[tid + i * 256];
        // activation slice for k = kb + lane (coherent; independent of ldsTile)
        float v0 = cload(&g_p1q1[db0 + 0][dn * 512 + kb + lane]);
        float v1 = cload(&g_p1q1[db0 + 1][dn * 512 + kb + lane]);
        float v2 = cload(&g_p1q1[db0 + 2][dn * 512 + kb + lane]);
        float v3 = cload(&g_p1q1[db0 + 3][dn * 512 + kb + lane]);
        __syncthreads();
#pragma unroll
        for (int kk = 0; kk < 64; ++kk) {
          float w = ldsTile[kk * 256 + myc];
          acc0 = fmaf(rdlane(v0, kk), w, acc0);
          acc1 = fmaf(rdlane(v1, kk), w, acc1);
          acc2 = fmaf(rdlane(v2, kk), w, acc2);
          acc3 = fmaf(rdlane(v3, kk), w, acc3);
        }
        __syncthreads();
      }
      float* lg = lds;   // 1024 floats: logits [i][256]
      float bb = bias2[dcolbase + myc];
      float s0 = acc0 + bb, s1 = acc1 + bb, s2 = acc2 + bb, s3 = acc3 + bb;
      lg[0 * 256 + myc] = s0;
      lg[1 * 256 + myc] = s1;
      lg[2 * 256 + myc] = s2;
      lg[3 * 256 + myc] = s3;
      const size_t obase = (dn ? 12800 : 8704) + dcolbase + myc;
      __builtin_nontemporal_store(s0, &P.out[((size_t)(db0 + 0) * TT + t) * OUTW + obase]);
      __builtin_nontemporal_store(s1, &P.out[((size_t)(db0 + 1) * TT + t) * OUTW + obase]);
      __builtin_nontemporal_store(s2, &P.out[((size_t)(db0 + 2) * TT + t) * OUTW + obase]);
      __builtin_nontemporal_store(s3, &P.out[((size_t)(db0 + 3) * TT + t) * OUTW + obase]);
      __syncthreads();
      const int b = db0 + kq;   // each wave samples its own batch row
      for (int r = 0; r < 4; ++r) {
        const int d = dcb * 4 + r;
        float L = lg[kq * 256 + r * 64 + lane];
        float m = L;
        for (int off = 1; off < 64; off <<= 1) m = fmaxf(m, __shfl_xor(m, off));
        float e = expf(L - m);
        float ssum = e;
        for (int off = 1; off < 64; off <<= 1) ssum += __shfl_xor(ssum, off);
        float p = 0.99f * (e / ssum) + (float)(0.01 / 64.0);
        unsigned flat = ((((unsigned)t * 32u + (unsigned)b) * 64u + (unsigned)d) * 64u +
                         (unsigned)lane) + ((unsigned)dn << 23);
        unsigned bits = jax_bits_partitionable(flat);
        float f = __uint_as_float((bits >> 9) | 0x3f800000u) - 1.0f;
        float u = fmaxf(1e-9f, f + 1e-9f);
        float g = -logf(-logf(u));
        float y = logf(p) + g;
        float vm = y; int idxm = lane;
        for (int off = 1; off < 64; off <<= 1) {
          float v2s = __shfl_xor(vm, off);
          int i2 = __shfl_xor(idxm, off);
          if (v2s > vm || (v2s == vm && i2 < idxm)) { vm = v2s; idxm = i2; }
        }
        __builtin_nontemporal_store(
            (lane == idxm) ? 1.0f : 0.0f,
            &P.out[((size_t)b * TT + t) * OUTW + (dn ? 4608 : 512) + d * 64 + lane]);
        if (dn == 1 && lane == 0) custore(&g_qidx[b][d], (unsigned)idxm);
      }
    }
    gbar(bid, tid, ++ph);
  }
}

// ---------------- host ----------------
extern "C" void kernel_launch(void* const* d_in, const int* in_sizes, int n_in,
                              void* d_out, int out_size, void* d_ws, size_t ws_size,
                              hipStream_t stream) {
  const float* obs   = (const float*)d_in[0];
  const float* act   = (const float*)d_in[1];
  const float* W_pre = (const float*)d_in[2];
  const float* b_pre = (const float*)d_in[3];
  const float* W_ih  = (const float*)d_in[4];
  const float* b_ih  = (const float*)d_in[5];
  const float* W_hh  = (const float*)d_in[6];
  const float* b_hh  = (const float*)d_in[7];
  const float* W_p1  = (const float*)d_in[8];
  const float* b_p1  = (const float*)d_in[9];
  const float* W_p2  = (const float*)d_in[10];
  const float* b_p2  = (const float*)d_in[11];
  const float* W_q1  = (const float*)d_in[12];
  const float* b_q1  = (const float*)d_in[13];
  const float* W_q2  = (const float*)d_in[14];
  const float* b_q2  = (const float*)d_in[15];

  kzero<<<128, 256, 0, stream>>>();
  auto tg = [](int R, int C) { return dim3((unsigned)((C + 31) / 32), (unsigned)((R + 31) / 32)); };
  ktranspose<<<tg(512, 4098), 256, 0, stream>>>(W_pre, 0, 512, 4098);
  ktranspose<<<tg(1536, 512), 256, 0, stream>>>(W_ih, 1, 1536, 512);
  ktranspose<<<tg(1536, 512), 256, 0, stream>>>(W_hh, 2, 1536, 512);
  ktranspose<<<tg(512, 512), 256, 0, stream>>>(W_p1, 3, 512, 512);
  ktranspose<<<tg(512, 768), 256, 0, stream>>>(W_q1, 4, 512, 768);
  ktranspose<<<tg(4096, 512), 256, 0, stream>>>(W_p2, 5, 4096, 512);
  ktranspose<<<tg(4096, 512), 256, 0, stream>>>(W_q2, 6, 4096, 512);

  Params P{obs, act, b_pre, b_ih, b_hh, b_p1, b_p2, b_q1, b_q2, (float*)d_out};
  rssm_main<<<dim3(256), dim3(256), 0, stream>>>(P);
}